// Round 1
// baseline (462.810 us; speedup 1.0000x reference)
//
#include <hip/hip_runtime.h>

// W8A8 quantized linear on gfx950.
// Stage 1: quantize x -> int8 (ws), weight -> int8 (ws).
// Stage 2: i8 MFMA GEMM (exact integer accumulate) + fused dequant/bias.

using v4i = __attribute__((ext_vector_type(4))) int;

typedef const __attribute__((address_space(1))) signed char gc_t;
typedef __attribute__((address_space(3))) signed char lc_t;

constexpr int BM = 128;
constexpr int BN = 128;
constexpr int BK = 64;   // int8 elements per K-tile (64 B rows)

// ---- quantization helpers -------------------------------------------------

__device__ __forceinline__ int quant4(const float4 f, float s) {
    // clamp(x/s, -128, 127) then trunc-toward-zero, pack 4 int8 into one dword
    int a = (int)fminf(fmaxf(f.x / s, -128.0f), 127.0f);
    int b = (int)fminf(fmaxf(f.y / s, -128.0f), 127.0f);
    int c = (int)fminf(fmaxf(f.z / s, -128.0f), 127.0f);
    int d = (int)fminf(fmaxf(f.w / s, -128.0f), 127.0f);
    return (a & 0xff) | ((b & 0xff) << 8) | ((c & 0xff) << 16) | ((d & 0xff) << 24);
}

__device__ __forceinline__ int pack4i(const float4 f) {
    // weight values are already exact integers in [-128,127]
    return ((int)f.x & 0xff) | (((int)f.y & 0xff) << 8) |
           (((int)f.z & 0xff) << 16) | (((int)f.w & 0xff) << 24);
}

__global__ void quant_x_kernel(const float* __restrict__ x,
                               const float* __restrict__ scale,
                               int4* __restrict__ out, int n16) {
    const float s = scale[0];
    int i = blockIdx.x * blockDim.x + threadIdx.x;
    if (i >= n16) return;
    const float4* p = (const float4*)x + (size_t)i * 4;
    float4 f0 = p[0], f1 = p[1], f2 = p[2], f3 = p[3];
    int4 o;
    o.x = quant4(f0, s);
    o.y = quant4(f1, s);
    o.z = quant4(f2, s);
    o.w = quant4(f3, s);
    out[i] = o;
}

__global__ void quant_w_kernel(const float* __restrict__ w,
                               int4* __restrict__ out, int n16) {
    int i = blockIdx.x * blockDim.x + threadIdx.x;
    if (i >= n16) return;
    const float4* p = (const float4*)w + (size_t)i * 4;
    float4 f0 = p[0], f1 = p[1], f2 = p[2], f3 = p[3];
    int4 o;
    o.x = pack4i(f0);
    o.y = pack4i(f1);
    o.z = pack4i(f2);
    o.w = pack4i(f3);
    out[i] = o;
}

// ---- int8 GEMM: C[m][n] = sum_k A[m][k]*W[n][k], dequant + bias -----------

__global__ __launch_bounds__(256) void gemm_i8_kernel(
    const signed char* __restrict__ Aq,   // [M][K] int8
    const signed char* __restrict__ Wq,   // [N][K] int8
    const float* __restrict__ wscale,     // [N]
    const float* __restrict__ iscale,     // [1]
    const float* __restrict__ bias,       // [N]
    float* __restrict__ C,                // [M][N]
    int M, int N, int K)
{
    __shared__ signed char As[BM * BK];
    __shared__ signed char Bs[BN * BK];

    const int tid  = threadIdx.x;
    const int wave = tid >> 6;        // 0..3
    const int lane = tid & 63;
    const int wm   = (wave >> 1) * 64;  // wave's row offset in tile
    const int wn   = (wave & 1) * 64;   // wave's col offset in tile

    const int m0 = blockIdx.y * BM;
    const int n0 = blockIdx.x * BN;

    // staging: per global_load_lds inst, 64 lanes x 16B = 16 rows of 64B
    const int srow = lane >> 2;         // 0..15
    const int scol = (lane & 3) * 16;   // 0,16,32,48

    // MFMA fragment addressing (16x16x64 i8): row/col = lane&15, k-chunk = (lane>>4)*16
    const int fr = lane & 15;
    const int fk = (lane >> 4) * 16;

    v4i acc[4][4];
#pragma unroll
    for (int i = 0; i < 4; ++i)
#pragma unroll
        for (int j = 0; j < 4; ++j) acc[i][j] = (v4i){0, 0, 0, 0};

    const size_t Kz = (size_t)K;
    for (int k0 = 0; k0 < K; k0 += BK) {
        // ---- stage A-tile and B-tile (each wave: 2x16 rows of each) ----
#pragma unroll
        for (int c = 0; c < 2; ++c) {
            const int r = wave * 32 + c * 16;      // wave-uniform base row
            const signed char* ga = Aq + (size_t)(m0 + r + srow) * Kz + (k0 + scol);
            __builtin_amdgcn_global_load_lds((gc_t*)ga, (lc_t*)(As + r * BK), 16, 0, 0);
            const signed char* gb = Wq + (size_t)(n0 + r + srow) * Kz + (k0 + scol);
            __builtin_amdgcn_global_load_lds((gc_t*)gb, (lc_t*)(Bs + r * BK), 16, 0, 0);
        }
        __syncthreads();   // compiler emits vmcnt(0) drain before barrier

        // ---- LDS -> fragments (ds_read_b128) ----
        v4i af[4], bf[4];
#pragma unroll
        for (int t = 0; t < 4; ++t)
            af[t] = *(const v4i*)(As + (wm + t * 16 + fr) * BK + fk);
#pragma unroll
        for (int t = 0; t < 4; ++t)
            bf[t] = *(const v4i*)(Bs + (wn + t * 16 + fr) * BK + fk);

        // ---- 16 MFMAs: 4x4 grid of 16x16 output tiles ----
#pragma unroll
        for (int mt = 0; mt < 4; ++mt)
#pragma unroll
            for (int nt = 0; nt < 4; ++nt)
                acc[mt][nt] = __builtin_amdgcn_mfma_i32_16x16x64_i8(
                    af[mt], bf[nt], acc[mt][nt], 0, 0, 0);
        __syncthreads();
    }

    // ---- epilogue: dequant + bias ----
    // C/D layout (verified, dtype-independent): col = lane&15, row = (lane>>4)*4 + reg
    const float is = iscale[0];
#pragma unroll
    for (int nt = 0; nt < 4; ++nt) {
        const int col = n0 + wn + nt * 16 + fr;
        const float sc = wscale[col] * is;
        const float bv = bias[col];
#pragma unroll
        for (int mt = 0; mt < 4; ++mt) {
            const int rbase = m0 + wm + mt * 16 + (lane >> 4) * 4;
#pragma unroll
            for (int r = 0; r < 4; ++r) {
                C[(size_t)(rbase + r) * N + col] = (float)acc[mt][nt][r] * sc + bv;
            }
        }
    }
}

// ---- launch ---------------------------------------------------------------

extern "C" void kernel_launch(void* const* d_in, const int* in_sizes, int n_in,
                              void* d_out, int out_size, void* d_ws, size_t ws_size,
                              hipStream_t stream) {
    const float* x  = (const float*)d_in[0];   // [B,S,IN] fp32
    const float* qw = (const float*)d_in[1];   // [OUT,IN] fp32 (int8 values)
    const float* ws = (const float*)d_in[2];   // [OUT,1]
    const float* is = (const float*)d_in[3];   // [1]
    const float* bs = (const float*)d_in[4];   // [OUT]
    float* out = (float*)d_out;

    const int nx = in_sizes[0];   // 33554432 = M*K
    const int nw = in_sizes[1];   // 16777216 = N*K
    const int N  = in_sizes[4];   // 4096
    const int K  = nw / N;        // 4096
    const int M  = nx / K;        // 8192

    signed char* xq = (signed char*)d_ws;
    signed char* wq = (signed char*)d_ws + (size_t)nx;

    quant_x_kernel<<<nx / 16 / 256, 256, 0, stream>>>(x, is, (int4*)xq, nx / 16);
    quant_w_kernel<<<nw / 16 / 256, 256, 0, stream>>>(qw, (int4*)wq, nw / 16);

    dim3 grid(N / BN, M / BM);
    gemm_i8_kernel<<<grid, 256, 0, stream>>>(xq, wq, ws, is, bs, out, M, N, K);
}

// Round 2
// 378.064 us; speedup vs baseline: 1.2242x; 1.2242x over previous
//
#include <hip/hip_runtime.h>

// W8A8 quantized linear on gfx950.
// R2: coalesced quant kernels (1 float4/lane), GEMM with BK=128 + XOR-swizzled
// LDS (conflict-free ds_read_b128), i8 MFMA exact integer accumulate.

using v4i = __attribute__((ext_vector_type(4))) int;

typedef const __attribute__((address_space(1))) signed char gc_t;
typedef __attribute__((address_space(3))) signed char lc_t;

constexpr int BM = 128;
constexpr int BN = 128;
constexpr int BK = 128;   // int8 elements per K-tile (128 B rows)

// ---- quantization ---------------------------------------------------------

__device__ __forceinline__ int quant4(const float4 f, float s) {
    // clamp(x/s, -128, 127) then trunc-toward-zero, pack 4 int8 into one dword
    int a = (int)fminf(fmaxf(f.x / s, -128.0f), 127.0f);
    int b = (int)fminf(fmaxf(f.y / s, -128.0f), 127.0f);
    int c = (int)fminf(fmaxf(f.z / s, -128.0f), 127.0f);
    int d = (int)fminf(fmaxf(f.w / s, -128.0f), 127.0f);
    return (a & 0xff) | ((b & 0xff) << 8) | ((c & 0xff) << 16) | ((d & 0xff) << 24);
}

__global__ void quant_x_kernel(const float4* __restrict__ x,
                               const float* __restrict__ scale,
                               int* __restrict__ out, int n4) {
    const float s = scale[0];
    int i = blockIdx.x * blockDim.x + threadIdx.x;
    if (i >= n4) return;
    out[i] = quant4(x[i], s);    // 16B/lane coalesced load, 4B/lane store
}

__global__ void quant_w_kernel(const float4* __restrict__ w,
                               int* __restrict__ out, int n4) {
    int i = blockIdx.x * blockDim.x + threadIdx.x;
    if (i >= n4) return;
    float4 f = w[i];             // weight values are exact integers already
    out[i] = ((int)f.x & 0xff) | (((int)f.y & 0xff) << 8) |
             (((int)f.z & 0xff) << 16) | (((int)f.w & 0xff) << 24);
}

// ---- int8 GEMM: C[m][n] = sum_k A[m][k]*W[n][k], dequant + bias -----------
//
// LDS swizzle: global_load_lds forces LDS dest = base + lane*16, so we swizzle
// the GLOBAL source instead. LDS slot (row r, 16B-chunk c) holds global chunk
// (c ^ (r&7)). Staging rows-per-inst = 8 (128B rows), so r&7 == lane>>3 and the
// source chunk is a pure lane function. Fragment reads XOR the chunk back:
// every wave64 ds_read_b128 then hits each bank-quad exactly 2x (free).

__global__ __launch_bounds__(256, 4) void gemm_i8_kernel(
    const signed char* __restrict__ Aq,   // [M][K] int8
    const signed char* __restrict__ Wq,   // [N][K] int8
    const float* __restrict__ wscale,     // [N]
    const float* __restrict__ iscale,     // [1]
    const float* __restrict__ bias,       // [N]
    float* __restrict__ C,                // [M][N]
    int M, int N, int K)
{
    __shared__ signed char As[BM * BK];   // 16 KB
    __shared__ signed char Bs[BN * BK];   // 16 KB

    const int tid  = threadIdx.x;
    const int wave = tid >> 6;          // 0..3
    const int lane = tid & 63;
    const int wm   = (wave >> 1) * 64;  // wave's row offset in tile
    const int wn   = (wave & 1) * 64;   // wave's col offset in tile

    const int m0 = blockIdx.y * BM;
    const int n0 = blockIdx.x * BN;

    // staging: per inst, 64 lanes x 16B = 8 rows of 128B. LDS slot chunk =
    // lane&7, LDS row low bits = lane>>3 -> global chunk = (lane&7)^(lane>>3).
    const int srow = lane >> 3;                      // 0..7
    const int gchunk = (lane & 7) ^ srow;            // swizzled source chunk

    // MFMA fragment addressing (16x16x64 i8): row = lane&15, k-quarter = lane>>4
    const int fr = lane & 15;
    const int qh = lane >> 4;
    // swizzled LDS chunk offsets for kstep s: ((s*4 + qh) ^ (fr&7)) * 16
    const int coff0 = (((0 * 4) + qh) ^ (fr & 7)) * 16;
    const int coff1 = (((1 * 4) + qh) ^ (fr & 7)) * 16;

    v4i acc[4][4];
#pragma unroll
    for (int i = 0; i < 4; ++i)
#pragma unroll
        for (int j = 0; j < 4; ++j) acc[i][j] = (v4i){0, 0, 0, 0};

    const size_t Kz = (size_t)K;
    // running global pointers: row (m0 + wave*32 + srow), byte column gchunk*16
    const signed char* pA = Aq + (size_t)(m0 + wave * 32 + srow) * Kz + gchunk * 16;
    const signed char* pB = Wq + (size_t)(n0 + wave * 32 + srow) * Kz + gchunk * 16;
    lc_t* lA = (lc_t*)(As + (wave * 32) * BK);
    lc_t* lB = (lc_t*)(Bs + (wave * 32) * BK);

    for (int k0 = 0; k0 < K; k0 += BK) {
        // ---- stage A-tile and B-tile: 4 insts each per wave (8 rows/inst) ----
#pragma unroll
        for (int c = 0; c < 4; ++c) {
            __builtin_amdgcn_global_load_lds((gc_t*)(pA + (size_t)(c * 8) * Kz),
                                             lA + c * 8 * BK, 16, 0, 0);
            __builtin_amdgcn_global_load_lds((gc_t*)(pB + (size_t)(c * 8) * Kz),
                                             lB + c * 8 * BK, 16, 0, 0);
        }
        pA += BK;
        pB += BK;
        __syncthreads();

        // ---- two k-steps of 64 within the 128-wide tile ----
#pragma unroll
        for (int s = 0; s < 2; ++s) {
            const int coff = s ? coff1 : coff0;
            v4i af[4], bf[4];
#pragma unroll
            for (int t = 0; t < 4; ++t)
                af[t] = *(const v4i*)(As + (wm + t * 16 + fr) * BK + coff);
#pragma unroll
            for (int t = 0; t < 4; ++t)
                bf[t] = *(const v4i*)(Bs + (wn + t * 16 + fr) * BK + coff);
#pragma unroll
            for (int mt = 0; mt < 4; ++mt)
#pragma unroll
                for (int nt = 0; nt < 4; ++nt)
                    acc[mt][nt] = __builtin_amdgcn_mfma_i32_16x16x64_i8(
                        af[mt], bf[nt], acc[mt][nt], 0, 0, 0);
        }
        __syncthreads();
    }

    // ---- epilogue: dequant + bias ----
    // C/D layout (HW-verified, dtype-independent): col = lane&15, row = qh*4 + reg
    const float is = iscale[0];
#pragma unroll
    for (int nt = 0; nt < 4; ++nt) {
        const int col = n0 + wn + nt * 16 + fr;
        const float sc = wscale[col] * is;
        const float bv = bias[col];
#pragma unroll
        for (int mt = 0; mt < 4; ++mt) {
            const int rbase = m0 + wm + mt * 16 + qh * 4;
#pragma unroll
            for (int r = 0; r < 4; ++r) {
                C[(size_t)(rbase + r) * N + col] = (float)acc[mt][nt][r] * sc + bv;
            }
        }
    }
}

// ---- launch ---------------------------------------------------------------

extern "C" void kernel_launch(void* const* d_in, const int* in_sizes, int n_in,
                              void* d_out, int out_size, void* d_ws, size_t ws_size,
                              hipStream_t stream) {
    const float* x  = (const float*)d_in[0];   // [B,S,IN] fp32
    const float* qw = (const float*)d_in[1];   // [OUT,IN] fp32 (int8 values)
    const float* ws = (const float*)d_in[2];   // [OUT,1]
    const float* is = (const float*)d_in[3];   // [1]
    const float* bs = (const float*)d_in[4];   // [OUT]
    float* out = (float*)d_out;

    const int nx = in_sizes[0];   // M*K
    const int nw = in_sizes[1];   // N*K
    const int N  = in_sizes[4];   // 4096
    const int K  = nw / N;        // 4096
    const int M  = nx / K;        // 8192

    signed char* xq = (signed char*)d_ws;
    signed char* wq = (signed char*)d_ws + (size_t)nx;

    quant_x_kernel<<<nx / 4 / 256, 256, 0, stream>>>(
        (const float4*)x, is, (int*)xq, nx / 4);
    quant_w_kernel<<<nw / 4 / 256, 256, 0, stream>>>(
        (const float4*)qw, (int*)wq, nw / 4);

    dim3 grid(N / BN, M / BM);
    gemm_i8_kernel<<<grid, 256, 0, stream>>>(xq, wq, ws, is, bs, out, M, N, K);
}